// Round 4
// baseline (7265.159 us; speedup 1.0000x reference)
//
#include <hip/hip_runtime.h>
#include <cmath>

// Problem constants (from reference): B=64, T=4096, D_IN=128, D_H=128, fp32.
#define BB   64
#define TT   4096
#define DIN  128
#define DH   128
#define GROWS  64   // rows staged per LDS buffer in the GEMM
#define NCHUNK 4    // chunks per block -> 256 rows/block

typedef float v2f __attribute__((ext_vector_type(2)));
typedef float v4f __attribute__((ext_vector_type(4)));

// Packed dual-fp32 FMA: acc += a * b (VOP3P).
__device__ __forceinline__ void pk_fma(v2f& acc, v2f a, v2f b) {
    asm("v_pk_fma_f32 %0, %1, %2, %0" : "+v"(acc) : "v"(a), "v"(b));
}
// acc += {a.x, a.x} * b   (op_sel broadcasts src0 low word to both halves)
__device__ __forceinline__ void pk_fma_blo(v2f& acc, v2f a, v2f b) {
    asm("v_pk_fma_f32 %0, %1, %2, %0 op_sel:[0,0,0] op_sel_hi:[0,1,1]"
        : "+v"(acc) : "v"(a), "v"(b));
}
// acc += {a.y, a.y} * b   (both halves use src0 high word)
__device__ __forceinline__ void pk_fma_bhi(v2f& acc, v2f a, v2f b) {
    asm("v_pk_fma_f32 %0, %1, %2, %0 op_sel:[1,0,0] op_sel_hi:[1,1,1]"
        : "+v"(acc) : "v"(a), "v"(b));
}

// tanh(x) = 1 - 2/(exp2(2*log2e*x) + 1). Branch-free; +-inf correct.
__device__ __forceinline__ float fast_tanh(float x) {
    float e = exp2f(x * 2.885390081777927f);           // 2*log2(e)
    float r = __builtin_amdgcn_rcpf(e + 1.0f);
    return __builtin_fmaf(-2.0f, r, 1.0f);
}

// ---------------------------------------------------------------------------
// Kernel 1: P = x @ Wx + b  -> written into d_out (consumed/overwritten by
// the scan). 256 threads = 2 row-groups x 128 cols; 4 chunks of 64 rows per
// block with double-buffered LDS staging (one barrier per chunk). Wx column
// j is loaded ONCE per block: all 128 loads issued back-to-back, THEN pinned
// (the R3 per-pair pin forced 64 serialized vmcnt(0) waits -> ~12K wasted
// cycles per block).
// ---------------------------------------------------------------------------
__global__ __launch_bounds__(256, 2) void xwx_gemm(const float* __restrict__ x,
                                                   const float* __restrict__ Wx,
                                                   const float* __restrict__ bias,
                                                   float* __restrict__ P) {
    __shared__ v4f xs4[2][GROWS * DIN / 4];   // 2 x 32 KiB
    const int tid = threadIdx.x;
    const size_t row0 = (size_t)blockIdx.x * (GROWS * NCHUNK);

    const int j  = tid & (DH - 1);
    const int rg = tid >> 7;   // 0 or 1: which 32-row half of the chunk

    // Wx column j -> 64 float2 pairs: issue ALL loads first, pin AFTER.
    v2f wj2[DIN / 2];
#pragma unroll
    for (int m = 0; m < DIN / 2; ++m) {
        wj2[m].x = Wx[(2 * m + 0) * DH + j];
        wj2[m].y = Wx[(2 * m + 1) * DH + j];
    }
#pragma unroll
    for (int m = 0; m < DIN / 2; ++m) asm("" : "+v"(wj2[m]));
    const float bj = bias[j];

    // Stage chunk 0
    {
        const v4f* xg = (const v4f*)x + row0 * (DIN / 4);
#pragma unroll
        for (int i = 0; i < (GROWS * DIN / 4) / 256; ++i)
            xs4[0][tid + i * 256] = xg[tid + i * 256];
    }
    __syncthreads();

#pragma unroll 1
    for (int c = 0; c < NCHUNK; ++c) {
        // Prefetch next chunk into the other LDS buffer (no conflict with
        // current reads; the end-of-chunk barrier publishes it).
        if (c + 1 < NCHUNK) {
            const v4f* xg = (const v4f*)x + (row0 + (size_t)(c + 1) * GROWS) * (DIN / 4);
#pragma unroll
            for (int i = 0; i < (GROWS * DIN / 4) / 256; ++i)
                xs4[(c + 1) & 1][tid + i * 256] = xg[tid + i * 256];
        }

        const size_t r0 = row0 + (size_t)c * GROWS;
#pragma unroll 1
        for (int r = 0; r < GROWS / 2; ++r) {
            const v4f* xr = xs4[c & 1] + (rg * (GROWS / 2) + r) * (DIN / 4);
            v2f a0 = {0.f, 0.f}, a1 = {0.f, 0.f}, a2 = {0.f, 0.f}, a3 = {0.f, 0.f};
#pragma unroll
            for (int k4 = 0; k4 < DIN / 4; k4 += 2) {
                v4f ha = xr[k4];       // broadcast ds_read_b128
                v4f hb = xr[k4 + 1];
                v2f ha01 = {ha.x, ha.y}, ha23 = {ha.z, ha.w};
                v2f hb01 = {hb.x, hb.y}, hb23 = {hb.z, hb.w};
                pk_fma(a0, ha01, wj2[2 * k4 + 0]);
                pk_fma(a1, ha23, wj2[2 * k4 + 1]);
                pk_fma(a2, hb01, wj2[2 * k4 + 2]);
                pk_fma(a3, hb23, wj2[2 * k4 + 3]);
            }
            float s = ((a0.x + a0.y) + (a1.x + a1.y)) + ((a2.x + a2.y) + (a3.x + a3.y));
            P[(r0 + rg * (GROWS / 2) + r) * DH + j] = s + bj;
        }
        __syncthreads();
    }
}

// ---------------------------------------------------------------------------
// Kernel 2: sequential scan — SINGLE WAVE per batch (64 blocks x 64 threads).
// Lane l owns columns 2l and 2l+1; W_h rows held as 128 pinned v2f (256
// VGPRs, fits the 512-VGPR budget at 1 wave/SIMD). h ping-pongs in 512B LDS;
// a single wave needs NO s_barrier — just s_waitcnt lgkmcnt(0) between the
// h-publish (ds_write_b64) and the next step's broadcast reads. This deletes
// the R3 bottleneck (per-step cross-wave barrier + LDS round-trip ~1050 cyc).
// The h[k] value needed by both packed lanes is broadcast for free via
// VOP3P op_sel (no duplication movs, no duplicated LDS).
// P is read 8 steps ahead and the same buffer is overwritten in place with h
// (loads for [tg+8,tg+16) are issued before stores to [tg,tg+8): disjoint).
// ---------------------------------------------------------------------------
__global__ __launch_bounds__(64, 1) void rnn_scan(float* po,   // P in, h out (aliased!)
                                                  const float* __restrict__ Wh) {
    const int b = blockIdx.x;
    const int l = threadIdx.x;   // 0..63

    __shared__ alignas(16) v2f hbuf[2][DH / 2];   // ping-pong h, 2 x 512 B

    // W_h row k, cols (2l, 2l+1): coalesced v2f loads (64 lanes x 8B = 512B
    // per k). Issue all 128 loads back-to-back, THEN pin.
    v2f w[DH];
#pragma unroll
    for (int k = 0; k < DH; ++k)
        w[k] = *(const v2f*)(Wh + (size_t)k * DH + 2 * l);
#pragma unroll
    for (int k = 0; k < DH; ++k) asm("" : "+v"(w[k]));

    float* pbase = po + (size_t)b * TT * DH + 2 * l;   // lane's column pair

    // First P batch (steps 0..7), v2f coalesced
    v2f pc[8], pn[8];
#pragma unroll
    for (int i = 0; i < 8; ++i) pc[i] = *(const v2f*)(pbase + (size_t)i * DH);

    hbuf[0][l] = v2f{0.f, 0.f};   // h_0 = 0
    asm volatile("s_waitcnt lgkmcnt(0)" ::: "memory");

#pragma unroll 1
    for (int tg = 0; tg < TT; tg += 8) {
        // Issue next P batch (consumed 8 steps later; clamp keeps addresses
        // valid on the last group — clamped loads are issued BEFORE the
        // stores to those addresses and their values are never used).
#pragma unroll
        for (int i = 0; i < 8; ++i) {
            int tl = tg + 8 + i;
            tl = (tl < TT) ? tl : (TT - 1);
            pn[i] = *(const v2f*)(pbase + (size_t)tl * DH);
        }

#pragma unroll
        for (int u = 0; u < 8; ++u) {
            // step t = tg+u reads hbuf[u&1], writes hbuf[(u+1)&1]
            const v4f* h4 = (const v4f*)hbuf[u & 1];   // uniform addr -> broadcast
            v2f a0 = {pc[u].x, pc[u].y}, a1 = {0.f, 0.f}, a2 = {0.f, 0.f}, a3 = {0.f, 0.f};
#pragma unroll
            for (int q = 0; q < DH / 4; ++q) {         // 32 x ds_read_b128
                v4f hv = h4[q];
                v2f h01 = {hv.x, hv.y};
                v2f h23 = {hv.z, hv.w};
                pk_fma_blo(a0, h01, w[4 * q + 0]);     // h[4q]   * Wh row
                pk_fma_bhi(a1, h01, w[4 * q + 1]);     // h[4q+1] * Wh row
                pk_fma_blo(a2, h23, w[4 * q + 2]);     // h[4q+2] * Wh row
                pk_fma_bhi(a3, h23, w[4 * q + 3]);     // h[4q+3] * Wh row
            }
            v2f s2 = (a0 + a1) + (a2 + a3);
            v2f hnew = {fast_tanh(s2.x), fast_tanh(s2.y)};

            *(v2f*)(pbase + (size_t)(tg + u) * DH) = hnew;  // out (overwrites P[t])
            hbuf[(u + 1) & 1][l] = hnew;                    // publish h_t
            // Single-wave sync: wait own ds_write only; no barrier, vmcnt
            // (prefetch loads + output stores) stays in flight.
            asm volatile("s_waitcnt lgkmcnt(0)" ::: "memory");
        }

#pragma unroll
        for (int i = 0; i < 8; ++i) pc[i] = pn[i];   // register rotate
    }
}

extern "C" void kernel_launch(void* const* d_in, const int* in_sizes, int n_in,
                              void* d_out, int out_size, void* d_ws, size_t ws_size,
                              hipStream_t stream) {
    const float* x    = (const float*)d_in[0];   // (B, T, DIN)
    const float* Wx   = (const float*)d_in[1];   // (DIN, DH)
    const float* Wh   = (const float*)d_in[2];   // (DH, DH)
    const float* bias = (const float*)d_in[3];   // (DH,)
    float* out = (float*)d_out;                  // (B, T, DH)

    // Phase 1: P = x @ Wx + b  -> written into d_out
    const int nblk = (BB * TT) / (GROWS * NCHUNK);   // 1024 blocks
    xwx_gemm<<<nblk, 256, 0, stream>>>(x, Wx, bias, out);

    // Phase 2: sequential scan, in-place on d_out (one wave per batch)
    rnn_scan<<<BB, 64, 0, stream>>>(out, Wh);
}